// Round 1
// baseline (95.506 us; speedup 1.0000x reference)
//
#include <hip/hip_runtime.h>
#include <math.h>

// Fused int8-dequant -> causal mask -> softmax -> int8-requant.
// B=4, H=16, S=1024. Input/output int8 materialized as int32 by harness.
// One 256-thread block per row; each thread owns 4 contiguous columns.

__global__ __launch_bounds__(256) void fused_causal_softmax_q(
    const int* __restrict__ xq,          // [B*H*S, S] int32 (int8 values)
    const float* __restrict__ scale_x,   // [H*S]
    const float* __restrict__ scale_out, // [H*S]
    int* __restrict__ out)               // [B*H*S, S] int32 (int8 values)
{
    constexpr int S  = 1024;
    constexpr int HS = 16 * S;

    const int row = blockIdx.x;          // b*H*S + h*S + i
    const int hs  = row & (HS - 1);      // h*S + i  (scale index)
    const int i   = hs & (S - 1);        // row within the S x S tile
    const int t   = threadIdx.x;         // 0..255

    const size_t base = (size_t)row * S;
    const int4* __restrict__ xin = (const int4*)(xq + base);
    int4* __restrict__ ov        = (int4*)(out + base);

    const float sx = scale_x[hs];

    const int j0     = t << 2;           // first column this thread owns
    const int nvalid = i - j0 + 1;       // how many of our 4 cols are <= diagonal

    float v0 = -INFINITY, v1 = -INFINITY, v2 = -INFINITY, v3 = -INFINITY;
    if (nvalid > 0) {
        int4 q = xin[t];                 // 16B coalesced load (skipped past diagonal)
        v0 = (float)q.x * sx;
        if (nvalid > 1) v1 = (float)q.y * sx;
        if (nvalid > 2) v2 = (float)q.z * sx;
        if (nvalid > 3) v3 = (float)q.w * sx;
    }

    // ---- block max reduce (4 waves of 64) ----
    float m = fmaxf(fmaxf(v0, v1), fmaxf(v2, v3));
    #pragma unroll
    for (int off = 32; off > 0; off >>= 1)
        m = fmaxf(m, __shfl_xor(m, off));

    __shared__ float redm[4];
    __shared__ float reds[4];
    const int wid = t >> 6;
    if ((t & 63) == 0) redm[wid] = m;
    __syncthreads();
    m = fmaxf(fmaxf(redm[0], redm[1]), fmaxf(redm[2], redm[3]));

    // ---- exp + block sum reduce ----
    const float e0 = __expf(v0 - m);     // -inf inputs -> exactly 0
    const float e1 = __expf(v1 - m);
    const float e2 = __expf(v2 - m);
    const float e3 = __expf(v3 - m);
    float s = (e0 + e1) + (e2 + e3);
    #pragma unroll
    for (int off = 32; off > 0; off >>= 1)
        s += __shfl_xor(s, off);
    if ((t & 63) == 0) reds[wid] = s;
    __syncthreads();
    s = (reds[0] + reds[1]) + (reds[2] + reds[3]);

    // p = e/s ; out = clip(round(p / so), -128, 127). p >= 0 so only the upper
    // clip matters. Fold 1/(s*so) into one multiply. rintf == round-half-even
    // which matches jnp.round.
    const float k = 1.0f / (s * scale_out[hs]);

    int4 r;
    r.x = (int)fminf(rintf(e0 * k), 127.0f);
    r.y = (int)fminf(rintf(e1 * k), 127.0f);
    r.z = (int)fminf(rintf(e2 * k), 127.0f);
    r.w = (int)fminf(rintf(e3 * k), 127.0f);
    ov[t] = r;                           // 16B coalesced store (full row: zeros past diagonal)
}

extern "C" void kernel_launch(void* const* d_in, const int* in_sizes, int n_in,
                              void* d_out, int out_size, void* d_ws, size_t ws_size,
                              hipStream_t stream) {
    const int*   xq = (const int*)d_in[0];
    const float* sx = (const float*)d_in[1];
    const float* so = (const float*)d_in[2];
    int* out = (int*)d_out;

    constexpr int B = 4, H = 16, S = 1024;
    const int rows = B * H * S;          // 65536 blocks, one per row
    fused_causal_softmax_q<<<dim3(rows), dim3(256), 0, stream>>>(xq, sx, so, out);
}

// Round 2
// 82.803 us; speedup vs baseline: 1.1534x; 1.1534x over previous
//
#include <hip/hip_runtime.h>
#include <math.h>

// Fused int8-dequant -> causal mask -> softmax -> int8-requant.
// B=4, H=16, S=1024. Input/output int8 materialized as int32 by harness.
// One 64-lane WAVE per row (4 rows per 256-thread block): no barriers, no LDS.
// Lane owns 16 cols as 4 chunks: col = k*256 + lane*4 (each chunk = one int4,
// each wave-load = contiguous 1KB, fully coalesced).

__global__ __launch_bounds__(256) void fused_causal_softmax_q(
    const int* __restrict__ xq,          // [B*H*S, S] int32 (int8 values)
    const float* __restrict__ scale_x,   // [H*S]
    const float* __restrict__ scale_out, // [H*S]
    int* __restrict__ out)               // [B*H*S, S] int32 (int8 values)
{
    constexpr int S  = 1024;
    constexpr int HS = 16 * S;

    const int wid  = threadIdx.x >> 6;           // wave id 0..3
    const int lane = threadIdx.x & 63;
    const int row  = (blockIdx.x << 2) + wid;    // one row per wave
    const int hs   = row & (HS - 1);             // h*S + i  (scale index)
    const int i    = hs & (S - 1);               // row within the S x S tile

    const size_t base = (size_t)row * S;
    const int4* __restrict__ xin = (const int4*)(xq + base);
    int4* __restrict__ ov        = (int4*)(out + base);

    const float sx = scale_x[hs];
    const float so = scale_out[hs];

    // ---- load + dequant + causal mask (4 independent coalesced loads) ----
    float v[16];
    #pragma unroll
    for (int k = 0; k < 4; ++k) {
        const int j0 = (k << 8) + (lane << 2);   // first col of this chunk
        const int nv = i - j0 + 1;               // valid elems in this int4
        if (nv > 0) {
            int4 q = xin[(k << 6) + lane];
            v[k*4+0] = (float)q.x * sx;
            v[k*4+1] = (nv > 1) ? (float)q.y * sx : -INFINITY;
            v[k*4+2] = (nv > 2) ? (float)q.z * sx : -INFINITY;
            v[k*4+3] = (nv > 3) ? (float)q.w * sx : -INFINITY;
        } else {
            v[k*4+0] = -INFINITY; v[k*4+1] = -INFINITY;
            v[k*4+2] = -INFINITY; v[k*4+3] = -INFINITY;
        }
    }

    // ---- wave max reduce ----
    float m = v[0];
    #pragma unroll
    for (int e = 1; e < 16; ++e) m = fmaxf(m, v[e]);
    #pragma unroll
    for (int off = 32; off > 0; off >>= 1)
        m = fmaxf(m, __shfl_xor(m, off));

    // ---- exp + wave sum reduce ----
    float s = 0.0f;
    #pragma unroll
    for (int e = 0; e < 16; ++e) {
        v[e] = __expf(v[e] - m);                 // -inf -> exactly 0
        s += v[e];
    }
    #pragma unroll
    for (int off = 32; off > 0; off >>= 1)
        s += __shfl_xor(s, off);

    // out = clip(round(p / so), -128, 127); p = e/s >= 0 so only upper clip.
    // rintf == round-half-even, matches jnp.round.
    const float kf = 1.0f / (s * so);

    #pragma unroll
    for (int k = 0; k < 4; ++k) {
        int4 r;
        r.x = (int)fminf(rintf(v[k*4+0] * kf), 127.0f);
        r.y = (int)fminf(rintf(v[k*4+1] * kf), 127.0f);
        r.z = (int)fminf(rintf(v[k*4+2] * kf), 127.0f);
        r.w = (int)fminf(rintf(v[k*4+3] * kf), 127.0f);
        ov[(k << 6) + lane] = r;                 // contiguous 1KB wave store
    }
}

extern "C" void kernel_launch(void* const* d_in, const int* in_sizes, int n_in,
                              void* d_out, int out_size, void* d_ws, size_t ws_size,
                              hipStream_t stream) {
    const int*   xq = (const int*)d_in[0];
    const float* sx = (const float*)d_in[1];
    const float* so = (const float*)d_in[2];
    int* out = (int*)d_out;

    constexpr int B = 4, H = 16, S = 1024;
    const int rows = B * H * S;                  // 65536 rows
    fused_causal_softmax_q<<<dim3(rows / 4), dim3(256), 0, stream>>>(xq, sx, so, out);
}

// Round 3
// 75.413 us; speedup vs baseline: 1.2664x; 1.0980x over previous
//
#include <hip/hip_runtime.h>
#include <math.h>

// Fused int8-dequant -> causal mask -> softmax -> int8-requant.
// B=4, H=16, S=1024. Input/output int8 materialized as int32 by harness.
// One 64-lane WAVE per row; 4 rows per 256-thread block with MIRROR PAIRING:
// waves 0,1 take rows 2b,2b+1 (front), waves 2,3 take the mirrored rows from
// the back -> every block reads ~2 full rows regardless of b (balanced).
// Nontemporal loads/stores: data is streamed exactly once, skip L2 churn.

typedef int int4v __attribute__((ext_vector_type(4)));

__global__ __launch_bounds__(256, 8) void fused_causal_softmax_q(
    const int* __restrict__ xq,          // [B*H*S, S] int32 (int8 values)
    const float* __restrict__ scale_x,   // [H*S]
    const float* __restrict__ scale_out, // [H*S]
    int* __restrict__ out)               // [B*H*S, S] int32 (int8 values)
{
    constexpr int S    = 1024;
    constexpr int HS   = 16 * S;
    constexpr int ROWS = 4 * HS;                 // 65536

    const int wid  = threadIdx.x >> 6;           // wave id 0..3
    const int lane = threadIdx.x & 63;
    const int fr   = (blockIdx.x << 1) + (wid & 1);
    const int row  = (wid < 2) ? fr : (ROWS - 1 - fr);   // mirror pairing
    const int hs   = row & (HS - 1);             // h*S + i  (scale index)
    const int i    = hs & (S - 1);               // row within the S x S tile

    const size_t base = (size_t)row * S;
    const int4v* __restrict__ xin = (const int4v*)(xq + base);
    int4v* __restrict__ ov        = (int4v*)(out + base);

    const float sx = scale_x[hs];
    const float so = scale_out[hs];

    // ---- load + dequant + causal mask (4 independent coalesced nt loads) ----
    float v[16];
    #pragma unroll
    for (int k = 0; k < 4; ++k) {
        const int j0 = (k << 8) + (lane << 2);   // first col of this chunk
        const int nv = i - j0 + 1;               // valid elems in this int4
        if (nv > 0) {
            int4v q = __builtin_nontemporal_load(&xin[(k << 6) + lane]);
            v[k*4+0] = (float)q.x * sx;
            v[k*4+1] = (nv > 1) ? (float)q.y * sx : -INFINITY;
            v[k*4+2] = (nv > 2) ? (float)q.z * sx : -INFINITY;
            v[k*4+3] = (nv > 3) ? (float)q.w * sx : -INFINITY;
        } else {
            v[k*4+0] = -INFINITY; v[k*4+1] = -INFINITY;
            v[k*4+2] = -INFINITY; v[k*4+3] = -INFINITY;
        }
    }

    // ---- wave max reduce ----
    float m = v[0];
    #pragma unroll
    for (int e = 1; e < 16; ++e) m = fmaxf(m, v[e]);
    #pragma unroll
    for (int off = 32; off > 0; off >>= 1)
        m = fmaxf(m, __shfl_xor(m, off));

    // ---- exp + wave sum reduce ----
    float s = 0.0f;
    #pragma unroll
    for (int e = 0; e < 16; ++e) {
        v[e] = __expf(v[e] - m);                 // -inf -> exactly 0
        s += v[e];
    }
    #pragma unroll
    for (int off = 32; off > 0; off >>= 1)
        s += __shfl_xor(s, off);

    // out = clip(round(p / so), -128, 127); p = e/s >= 0 so only upper clip.
    // rintf == round-half-even, matches jnp.round.
    const float kf = 1.0f / (s * so);

    #pragma unroll
    for (int k = 0; k < 4; ++k) {
        int4v r;
        r.x = (int)fminf(rintf(v[k*4+0] * kf), 127.0f);
        r.y = (int)fminf(rintf(v[k*4+1] * kf), 127.0f);
        r.z = (int)fminf(rintf(v[k*4+2] * kf), 127.0f);
        r.w = (int)fminf(rintf(v[k*4+3] * kf), 127.0f);
        __builtin_nontemporal_store(r, &ov[(k << 6) + lane]);  // 1KB wave store
    }
}

extern "C" void kernel_launch(void* const* d_in, const int* in_sizes, int n_in,
                              void* d_out, int out_size, void* d_ws, size_t ws_size,
                              hipStream_t stream) {
    const int*   xq = (const int*)d_in[0];
    const float* sx = (const float*)d_in[1];
    const float* so = (const float*)d_in[2];
    int* out = (int*)d_out;

    constexpr int B = 4, H = 16, S = 1024;
    const int rows = B * H * S;                  // 65536 rows
    // each block covers 2 front rows + 2 mirrored back rows
    fused_causal_softmax_q<<<dim3(rows / 4), dim3(256), 0, stream>>>(xq, sx, so, out);
}